// Round 7
// baseline (425.569 us; speedup 1.0000x reference)
//
#include <hip/hip_runtime.h>
#include <stdint.h>

// Round 7: attn rewritten barrier-free. K and V^T MFMA A-fragments are loaded
// per-lane directly from global (dwordx4), no LDS, no barriers -> waves
// free-run and MFMA/VALU/VMEM overlap across 4 waves/SIMD. kv-tile = 32,
// register footprint ~120 VGPR, grid 1024 = exactly 4 blocks/CU (no tail).
// GEMMs and cvt kernels unchanged from R6 (swizzled LDS, XCD supertiles).

typedef __attribute__((ext_vector_type(8))) short short8;
typedef __attribute__((ext_vector_type(4))) float f32x4;
typedef __attribute__((ext_vector_type(16))) float f32x16;
typedef __attribute__((ext_vector_type(4))) unsigned int u32x4;
typedef __attribute__((ext_vector_type(4))) unsigned short us4;
typedef unsigned short ushort_t;
typedef unsigned int uint_t;

#define DMODEL 1024
#define SEQ 2048
#define NH 16
#define QSCALE 0.18033688011112043f  // (1/sqrt(64)) * log2(e)

__device__ __forceinline__ ushort_t bfbits(float f) {
  uint32_t u = __float_as_uint(f);
  u = (u + 0x7fffu + ((u >> 16) & 1u)) >> 16;  // RNE f32->bf16
  return (ushort_t)u;
}
__device__ __forceinline__ uint_t cvt_pk_bf16(float lo, float hi) {
  uint_t r;
  asm("v_cvt_pk_bf16_f32 %0, %1, %2" : "=v"(r) : "v"(lo), "v"(hi));
  return r;
}
__device__ __forceinline__ float exp2_hw(float x) {
  float r;
  asm("v_exp_f32 %0, %1" : "=v"(r) : "v"(x));
  return r;
}
__device__ __forceinline__ f32x16 mfma32(short8 a, short8 b, f32x16 c) {
  return __builtin_amdgcn_mfma_f32_32x32x16_bf16(a, b, c, 0, 0, 0);
}

typedef __attribute__((address_space(1))) void gvoid_t;
typedef __attribute__((address_space(3))) void lvoid_t;
__device__ __forceinline__ void gl_lds16(const void* gp, void* lp) {
  __builtin_amdgcn_global_load_lds((gvoid_t*)(uintptr_t)gp, (lvoid_t*)lp, 16, 0, 0);
}

// ---------------------------------------------------------------- cvt f32->bf16
__global__ __launch_bounds__(256) void cvt_bf16(const float* __restrict__ in,
                                                ushort_t* __restrict__ out) {
  int i = (int)(blockIdx.x * 256u + threadIdx.x) * 8;
  const float4* p = (const float4*)(in + i);
  float4 a = p[0], b = p[1];
  short8 o;
  o[0] = (short)bfbits(a.x); o[1] = (short)bfbits(a.y);
  o[2] = (short)bfbits(a.z); o[3] = (short)bfbits(a.w);
  o[4] = (short)bfbits(b.x); o[5] = (short)bfbits(b.y);
  o[6] = (short)bfbits(b.z); o[7] = (short)bfbits(b.w);
  *(short8*)(out + i) = o;
}

__global__ __launch_bounds__(256) void cvt4_bf16(const float* __restrict__ w0,
                                                 const float* __restrict__ w1,
                                                 const float* __restrict__ w2,
                                                 const float* __restrict__ w3,
                                                 ushort_t* __restrict__ out) {
  int which = (int)(blockIdx.x >> 9);
  const float* src = (which == 0) ? w0 : (which == 1) ? w1 : (which == 2) ? w2 : w3;
  int i = (int)(((blockIdx.x & 511) * 256u) + threadIdx.x) * 8;
  const float4* p = (const float4*)(src + i);
  float4 a = p[0], b = p[1];
  short8 o;
  o[0] = (short)bfbits(a.x); o[1] = (short)bfbits(a.y);
  o[2] = (short)bfbits(a.z); o[3] = (short)bfbits(a.w);
  o[4] = (short)bfbits(b.x); o[5] = (short)bfbits(b.y);
  o[6] = (short)bfbits(b.z); o[7] = (short)bfbits(b.w);
  *(short8*)(out + (size_t)which * 1048576 + i) = o;
}

// ---------------------------------------------------------------- GEMM (NT)
// C[M,N] = A[M,K] * Bw[N,K]^T + bias. 128x128 tile, BK=32, 4 waves (2x2).
// Triple-buffered LDS, one barrier per K-step: vmcnt -> barrier -> stage -> mfma.
// LDS 16B-chunk swizzle: chunk' = chunk ^ ((row>>1)&3)  (conflict-free b128).
#define EPI_QKV 0
#define EPI_OUT 1

template <int EPI>
__global__ __launch_bounds__(256) void gemm_bt(const ushort_t* __restrict__ A,
                                               const ushort_t* __restrict__ Bw,
                                               const float* __restrict__ b0,
                                               const float* __restrict__ b1,
                                               const float* __restrict__ b2,
                                               ushort_t* __restrict__ Qb,
                                               ushort_t* __restrict__ Kb,
                                               ushort_t* __restrict__ Vtb,
                                               float* __restrict__ Yf) {
  __shared__ alignas(16) ushort_t As[3][128 * 32];
  __shared__ alignas(16) ushort_t Bs[3][128 * 32];
  const int tid = threadIdx.x;
  const int lane = tid & 63, w = tid >> 6;
  const int g = lane >> 4, r16 = lane & 15;
  const int wr = w >> 1, wc = w & 1;

  // XCD-compact supertiles: each XCD gets a rectangle of blocks.
  int flat = (int)(blockIdx.x + gridDim.x * blockIdx.y);
  int xcd = flat & 7, local = flat >> 3;
  int bm0, bn0;
  if (EPI == EPI_QKV) {  // grid 64x24: per-XCD 16bm x 12bn
    bm0 = ((xcd & 3) * 16 + (local & 15)) * 128;
    bn0 = ((xcd >> 2) * 12 + (local >> 4)) * 128;
  } else {               // grid 64x8: per-XCD 8bm x 8bn
    bm0 = (xcd * 8 + (local & 7)) * 128;
    bn0 = (local >> 3) * 128;
  }

  f32x4 acc[4][4];
#pragma unroll
  for (int m = 0; m < 4; ++m)
#pragma unroll
    for (int n = 0; n < 4; ++n) acc[m][n] = (f32x4){0.f, 0.f, 0.f, 0.f};

  const int srow = tid >> 2;                              // row 0..63 (+64 2nd half)
  const int scs = ((tid & 3) ^ ((tid >> 3) & 3)) * 8;     // inverse-swizzled source chunk
  const int rsw = (r16 >> 1) & 3;                         // read-side chunk XOR

  auto stage = [&](int bf, int k0) {
    char* AsB = (char*)As[bf];
    char* BsB = (char*)Bs[bf];
    gl_lds16(A + (size_t)(bm0 + srow) * DMODEL + k0 + scs, AsB + w * 1024);
    gl_lds16(A + (size_t)(bm0 + 64 + srow) * DMODEL + k0 + scs, AsB + w * 1024 + 4096);
    gl_lds16(Bw + (size_t)(bn0 + srow) * DMODEL + k0 + scs, BsB + w * 1024);
    gl_lds16(Bw + (size_t)(bn0 + 64 + srow) * DMODEL + k0 + scs, BsB + w * 1024 + 4096);
  };

  stage(0, 0);
  stage(1, 32);
  int buf = 0;
  for (int t = 0; t < 32; ++t) {
    if (t < 31)
      asm volatile("s_waitcnt vmcnt(4)\n\ts_barrier" ::: "memory");
    else
      asm volatile("s_waitcnt vmcnt(0)\n\ts_barrier" ::: "memory");
    if (t < 30) stage((t + 2) % 3, (t + 2) * 32);

    const char* AsB = (const char*)As[buf];
    const char* BsB = (const char*)Bs[buf];
    short8 af[4], bfr[4];
#pragma unroll
    for (int m = 0; m < 4; ++m)
      af[m] = *(const short8*)(AsB + (wr * 64 + m * 16 + r16) * 64 + (g ^ rsw) * 16);
#pragma unroll
    for (int n = 0; n < 4; ++n)
      bfr[n] = *(const short8*)(BsB + (wc * 64 + n * 16 + r16) * 64 + (g ^ rsw) * 16);
    __builtin_amdgcn_s_setprio(1);
#pragma unroll
    for (int m = 0; m < 4; ++m)
#pragma unroll
      for (int n = 0; n < 4; ++n)
        acc[m][n] = __builtin_amdgcn_mfma_f32_16x16x32_bf16(af[m], bfr[n], acc[m][n], 0, 0, 0);
    __builtin_amdgcn_s_setprio(0);
    buf = (buf == 2) ? 0 : buf + 1;
  }

  if (EPI == EPI_OUT) {
    float bv[4];
#pragma unroll
    for (int n = 0; n < 4; ++n) bv[n] = b0[bn0 + wc * 64 + n * 16 + r16];
#pragma unroll
    for (int m = 0; m < 4; ++m)
#pragma unroll
      for (int r = 0; r < 4; ++r) {
        int grow = bm0 + wr * 64 + m * 16 + 4 * g + r;
        float* orow = Yf + (size_t)grow * DMODEL + bn0 + wc * 64;
#pragma unroll
        for (int n = 0; n < 4; ++n) orow[n * 16 + r16] = acc[m][n][r] + bv[n];
      }
  } else {
    int mat = bn0 >> 10;  // 0=Q 1=K 2=V (uniform per block)
    const float* bias = (mat == 0) ? b0 : (mat == 1 ? b1 : b2);
    ushort_t* dQK = (mat == 0) ? Qb : Kb;
    int nc0 = bn0 & 1023;
    float scl = (mat == 0) ? QSCALE : 1.0f;
    float bv[4];
#pragma unroll
    for (int n = 0; n < 4; ++n) bv[n] = bias[nc0 + wc * 64 + n * 16 + r16];
    if (mat < 2) {
#pragma unroll
      for (int m = 0; m < 4; ++m)
#pragma unroll
        for (int r = 0; r < 4; ++r) {
          int grow = bm0 + wr * 64 + m * 16 + 4 * g + r;
          int b = grow >> 11, s = grow & 2047;
#pragma unroll
          for (int n = 0; n < 4; ++n) {
            int gcl = nc0 + wc * 64 + n * 16 + r16;
            int h = gcl >> 6, d = gcl & 63;
            dQK[((size_t)(b * NH + h) * SEQ + s) * 64 + d] = bfbits((acc[m][n][r] + bv[n]) * scl);
          }
        }
    } else {
#pragma unroll
      for (int m = 0; m < 4; ++m) {
        int grow0 = bm0 + wr * 64 + m * 16 + 4 * g;
        int b = grow0 >> 11, s0 = grow0 & 2047;
#pragma unroll
        for (int n = 0; n < 4; ++n) {
          int gcl = nc0 + wc * 64 + n * 16 + r16;
          int h = gcl >> 6, d = gcl & 63;
          us4 pk;
          pk[0] = bfbits(acc[m][n][0] + bv[n]);
          pk[1] = bfbits(acc[m][n][1] + bv[n]);
          pk[2] = bfbits(acc[m][n][2] + bv[n]);
          pk[3] = bfbits(acc[m][n][3] + bv[n]);
          *(us4*)(Vtb + ((size_t)(b * NH + h) * 64 + d) * SEQ + s0) = pk;
        }
      }
    }
  }
}

// ---------------------------------------------------------------- attention
// grid 1024 x 256thr (4 waves). Wave w owns q rows [q0+32w, q0+32w+32).
// NO LDS, NO barriers: K and V^T A-fragments loaded per-lane from global
// (L1/L2-served; resident blocks share the head's K/V). kv-tile = 32.
// Static-m softmax (p=exp2(s)), in-register P via cvt_pk + permlane32_swap.
__global__ __launch_bounds__(256, 4) void attn_fwd(const ushort_t* __restrict__ Q,
                                                   const ushort_t* __restrict__ K,
                                                   const ushort_t* __restrict__ Vt,
                                                   ushort_t* __restrict__ ctx) {
  const int tid = threadIdx.x;
  const int lane = tid & 63, w = tid >> 6;  // w 0..3
  const int q32 = lane & 31, h = lane >> 5;

  int flat = (int)blockIdx.x;                // 1024 blocks
  int sw = (flat & 7) * 128 + (flat >> 3);   // XCD-chunked (bijective)
  int bh = sw >> 4, q0 = (sw & 15) * 128;

  const ushort_t* Qp = Q + (size_t)bh * SEQ * 64;
  const ushort_t* Kp = K + (size_t)bh * SEQ * 64 + (size_t)q32 * 64 + 8 * h;
  const ushort_t* Vp = Vt + (size_t)bh * 64 * SEQ + (size_t)q32 * SEQ + 8 * h;

  // Q B-frags: col=q=q32, chunk c covers d = 16c + 8h + v (pre-scaled)
  short8 qf[4];
  {
    const ushort_t* qr = Qp + (size_t)(q0 + w * 32 + q32) * 64 + h * 8;
    qf[0] = *(const short8*)(qr);
    qf[1] = *(const short8*)(qr + 16);
    qf[2] = *(const short8*)(qr + 32);
    qf[3] = *(const short8*)(qr + 48);
  }

  f32x16 o0 = (f32x16)0.0f, o1 = (f32x16)0.0f;
  float l = 0.f;

  // K A-frag (rows kv0+q32, d-slice 16c+8h+v): kf[c]
  short8 kf[4], vf[2][2];
  auto loadK = [&](int kv0) {
#pragma unroll
    for (int c = 0; c < 4; ++c)
      kf[c] = *(const short8*)(Kp + (size_t)kv0 * 64 + 16 * c);
  };
  // V^T A-frag (rows d=32db+q32, kv-slice kv0+16c2+8h+v): vf[db][c2]
  auto loadV = [&](int kv0) {
#pragma unroll
    for (int db = 0; db < 2; ++db)
#pragma unroll
      for (int c2 = 0; c2 < 2; ++c2)
        vf[db][c2] = *(const short8*)(Vp + (size_t)db * 32 * SEQ + kv0 + 16 * c2);
  };

  loadK(0);
  loadV(0);
#pragma unroll 1
  for (int t = 0; t < 64; ++t) {
    // QK^T: s[kv_local 0..31][q]
    f32x16 s = (f32x16)0.0f;
    __builtin_amdgcn_s_setprio(1);
#pragma unroll
    for (int c = 0; c < 4; ++c) s = mfma32(kf[c], qf[c], s);
    __builtin_amdgcn_s_setprio(0);
    if (t < 63) loadK((t + 1) * 32);  // hide K latency under softmax+PV

    // p = exp2(s) (static m); l += sum
#pragma unroll
    for (int j = 0; j < 16; ++j) s[j] = exp2_hw(s[j]);
    {
      float a = (s[0] + s[1]) + (s[2] + s[3]);
      float b = (s[4] + s[5]) + (s[6] + s[7]);
      float c2 = (s[8] + s[9]) + (s[10] + s[11]);
      float d = (s[12] + s[13]) + (s[14] + s[15]);
      l += (a + b) + (c2 + d);
    }

    // pack to bf16 pairs; permlane32_swap -> B-frags per 16-kv chunk
    uint_t pw[8];
#pragma unroll
    for (int i = 0; i < 8; ++i) pw[i] = cvt_pk_bf16(s[2 * i], s[2 * i + 1]);
#pragma unroll
    for (int c = 0; c < 2; ++c) {
      asm volatile("v_permlane32_swap_b32 %0, %1" : "+v"(pw[4 * c]), "+v"(pw[4 * c + 2]));
      asm volatile("v_permlane32_swap_b32 %0, %1" : "+v"(pw[4 * c + 1]), "+v"(pw[4 * c + 3]));
    }

    // PV: o[db] += V^T[d][kv chunk c2] * P
    __builtin_amdgcn_s_setprio(1);
#pragma unroll
    for (int c2 = 0; c2 < 2; ++c2) {
      u32x4 pk = {pw[4 * c2], pw[4 * c2 + 1], pw[4 * c2 + 2], pw[4 * c2 + 3]};
      short8 pfc = __builtin_bit_cast(short8, pk);
      o0 = mfma32(vf[0][c2], pfc, o0);
      o1 = mfma32(vf[1][c2], pfc, o1);
    }
    __builtin_amdgcn_s_setprio(0);
    if (t < 63) loadV((t + 1) * 32);  // hide V latency under QK+softmax
  }

  // epilogue: combine h-halves of l, normalize, store ctx [B,S,H*64]
  float ltot = l + __shfl_xor(l, 32);
  float inv = 1.0f / ltot;
  int b = bh >> 4, hd = bh & 15;
  uint_t* crow = (uint_t*)(ctx + ((size_t)(b * SEQ + q0 + w * 32 + q32)) * DMODEL + hd * 64);
#pragma unroll
  for (int i = 0; i < 8; ++i) {
    int ui = (i & 1) + 4 * (i >> 1) + 2 * h;  // d(reg 2i) = 2(i&1)+8(i>>1)+4h
    crow[ui] = cvt_pk_bf16(o0[2 * i] * inv, o0[2 * i + 1] * inv);
    crow[16 + ui] = cvt_pk_bf16(o1[2 * i] * inv, o1[2 * i + 1] * inv);
  }
}

// ---------------------------------------------------------------- launch
extern "C" void kernel_launch(void* const* d_in, const int* in_sizes, int n_in,
                              void* d_out, int out_size, void* d_ws, size_t ws_size,
                              hipStream_t stream) {
  (void)in_sizes; (void)n_in; (void)out_size; (void)ws_size;
  const float* x  = (const float*)d_in[0];
  const float* Wq = (const float*)d_in[1];
  const float* bq = (const float*)d_in[2];
  const float* Wk = (const float*)d_in[3];
  const float* bk = (const float*)d_in[4];
  const float* Wv = (const float*)d_in[5];
  const float* bv = (const float*)d_in[6];
  const float* Wo = (const float*)d_in[7];
  const float* bo = (const float*)d_in[8];
  float* out = (float*)d_out;

  ushort_t* xb  = (ushort_t*)d_ws;       // 8M elems
  ushort_t* w3  = xb + 8388608;          // 3M (Wq,Wk,Wv) + 1M (Wo) contiguous
  ushort_t* wob = w3 + 3145728;          // 1M
  ushort_t* Qb  = wob + 1048576;         // 8M  [B,H,S,64] (pre-scaled)
  ushort_t* Kb  = Qb + 8388608;          // 8M  [B,H,S,64]
  ushort_t* Vtb = Kb + 8388608;          // 8M  [B,H,64,S]
  ushort_t* cx  = Vtb + 8388608;         // 8M  [B,S,1024]

  cvt_bf16<<<4096, 256, 0, stream>>>(x, xb);
  cvt4_bf16<<<2048, 256, 0, stream>>>(Wq, Wk, Wv, Wo, w3);

  gemm_bt<EPI_QKV><<<dim3(64, 24), 256, 0, stream>>>(xb, w3, bq, bk, bv, Qb, Kb, Vtb, nullptr);
  attn_fwd<<<1024, 256, 0, stream>>>(Qb, Kb, Vtb, cx);
  gemm_bt<EPI_OUT><<<dim3(64, 8), 256, 0, stream>>>(cx, wob, bo, nullptr, nullptr,
                                                    nullptr, nullptr, nullptr, out);
}